// Round 3
// baseline (340.268 us; speedup 1.0000x reference)
//
#include <hip/hip_runtime.h>
#include <hip/hip_bf16.h>

#define DM 768
#define NH 12
#define HD 64
#define B_ 4
#define S_ 2048
#define MT (B_*S_)   // 8192 rows

typedef unsigned short u16;
typedef __attribute__((ext_vector_type(8))) short bf16x8;
typedef __attribute__((ext_vector_type(4))) float f32x4;
typedef __attribute__((ext_vector_type(4))) short s16x4;
typedef __attribute__((ext_vector_type(4))) unsigned u32x4;

__device__ __forceinline__ u16 f2bf(float f) {
    union { float f; unsigned u; } x; x.f = f;
    unsigned r = x.u + 0x7fffu + ((x.u >> 16) & 1u);   // RNE
    return (u16)(r >> 16);
}

__device__ __forceinline__ unsigned pk2(float a, float b) {
    union { __hip_bfloat162 h; unsigned u; } cv;
    cv.h = __float22bfloat162_rn(float2{a, b});
    return cv.u;
}

#define GLD_LDS(gp, lp) \
    __builtin_amdgcn_global_load_lds( \
        (const __attribute__((address_space(1))) void*)(gp), \
        (__attribute__((address_space(3))) void*)(lp), 16, 0, 0)

// ---------------- fused fp32 -> bf16 conversions ----------------
__global__ void cvt3_kernel(const float* __restrict__ s0, const float* __restrict__ s1,
                            const float* __restrict__ s2,
                            u16* __restrict__ d0, u16* __restrict__ d1, u16* __restrict__ d2,
                            int blocksPer) {
    int sel = blockIdx.x / blocksPer;           // uniform per block
    int rel = blockIdx.x % blocksPer;
    const float* s = (sel == 0) ? s0 : (sel == 1) ? s1 : s2;
    u16* d = (sel == 0) ? d0 : (sel == 1) ? d1 : d2;
    int i = (rel * 256 + threadIdx.x) * 4;
    float4 v = *(const float4*)(s + i);
    s16x4 o;
    o.x = (short)f2bf(v.x); o.y = (short)f2bf(v.y);
    o.z = (short)f2bf(v.z); o.w = (short)f2bf(v.w);
    *(s16x4*)(d + i) = o;
}

__global__ void cvt4_kernel(const float* __restrict__ s0, const float* __restrict__ s1,
                            const float* __restrict__ s2, const float* __restrict__ s3,
                            u16* __restrict__ d0, u16* __restrict__ d1,
                            u16* __restrict__ d2, u16* __restrict__ d3,
                            int blocksPer) {
    int sel = blockIdx.x / blocksPer;
    int rel = blockIdx.x % blocksPer;
    const float* s = (sel == 0) ? s0 : (sel == 1) ? s1 : (sel == 2) ? s2 : s3;
    u16* d = (sel == 0) ? d0 : (sel == 1) ? d1 : (sel == 2) ? d2 : d3;
    int i = (rel * 256 + threadIdx.x) * 4;
    float4 v = *(const float4*)(s + i);
    s16x4 o;
    o.x = (short)f2bf(v.x); o.y = (short)f2bf(v.y);
    o.z = (short)f2bf(v.z); o.w = (short)f2bf(v.w);
    *(s16x4*)(d + i) = o;
}

// ---------------- shared 128x128-tile MFMA core (m97 structure) ----------------
__device__ __forceinline__ void gemm_core_128(
    const u16* __restrict__ A, const u16* __restrict__ B,
    int m0, int n0, u16* As, u16* Bs, f32x4 acc[4][4])
{
    const int tid = threadIdx.x;
    const int lane = tid & 63;
    const int lr = lane & 15, quad = lane >> 4;
    const int wave = tid >> 6;
    const int wm = (wave & 1) * 64, wn = (wave >> 1) * 64;

    for (int ks = 0; ks < 24; ++ks) {
        #pragma unroll
        for (int r = 0; r < 2; ++r) {
            int idx = r * 256 + tid;
            int row = idx >> 2, col = (idx & 3) * 8;
            GLD_LDS(A + (size_t)(m0 + row) * DM + ks * 32 + col, As + idx * 8);
            GLD_LDS(B + (size_t)(n0 + row) * DM + ks * 32 + col, Bs + idx * 8);
        }
        __syncthreads();
        bf16x8 a[4], b[4];
        #pragma unroll
        for (int i = 0; i < 4; ++i) a[i] = *(const bf16x8*)(As + (wm + i * 16 + lr) * 32 + quad * 8);
        #pragma unroll
        for (int j = 0; j < 4; ++j) b[j] = *(const bf16x8*)(Bs + (wn + j * 16 + lr) * 32 + quad * 8);
        #pragma unroll
        for (int i = 0; i < 4; ++i)
            #pragma unroll
            for (int j = 0; j < 4; ++j)
                acc[i][j] = __builtin_amdgcn_mfma_f32_16x16x32_bf16(a[i], b[j], acc[i][j], 0, 0, 0);
        __syncthreads();
    }
}

// ---------------- fused QKV projection GEMM (LDS-staged) ----------------
__global__ __launch_bounds__(256) void qkv_gemm(
    const u16* __restrict__ Xq, const u16* __restrict__ Xk, const u16* __restrict__ Xv,
    const u16* __restrict__ Wq, const u16* __restrict__ Wk, const u16* __restrict__ Wv,
    const float* __restrict__ bQ, const float* __restrict__ bK, const float* __restrict__ bV,
    u16* __restrict__ Qo, u16* __restrict__ Ko, u16* __restrict__ VTo)
{
    __shared__ __align__(16) u16 As[128 * 32];
    __shared__ __align__(16) u16 Bs[128 * 32];

    const int mat = blockIdx.x / 384;           // uniform per block
    const int t   = blockIdx.x % 384;
    const int mt  = t / 6, nt = t % 6;
    const u16* X = (mat == 0) ? Xq : (mat == 1 ? Xk : Xv);
    const u16* W = (mat == 0) ? Wq : (mat == 1 ? Wk : Wv);
    const float* bias = (mat == 0) ? bQ : (mat == 1 ? bK : bV);

    const int lane = threadIdx.x & 63;
    const int lr = lane & 15, quad = lane >> 4;
    const int wave = threadIdx.x >> 6;
    const int m0 = mt * 128 + (wave & 1) * 64;
    const int n0 = nt * 128 + (wave >> 1) * 64;

    f32x4 acc[4][4] = {};
    gemm_core_128(X, W, mt * 128, nt * 128, As, Bs, acc);

    const int bb = m0 / S_, s0 = m0 % S_, h = n0 / HD;
    if (mat < 2) {
        u16* O = (mat == 0) ? Qo : Ko;
        const float qs = (mat == 0) ? 0.18033688011112042f : 1.0f;  // (1/8)*log2(e)
        #pragma unroll
        for (int jj = 0; jj < 4; ++jj) {
            float bv = bias[n0 + jj * 16 + lr];
            #pragma unroll
            for (int i = 0; i < 4; ++i)
                #pragma unroll
                for (int r = 0; r < 4; ++r) {
                    int s = s0 + i * 16 + quad * 4 + r;
                    O[((size_t)(bb * NH + h) * S_ + s) * HD + jj * 16 + lr] = f2bf((acc[i][jj][r] + bv) * qs);
                }
        }
    } else {
        #pragma unroll
        for (int jj = 0; jj < 4; ++jj) {
            float bv = bias[n0 + jj * 16 + lr];
            #pragma unroll
            for (int i = 0; i < 4; ++i) {
                int s = s0 + i * 16 + quad * 4;
                s16x4 o;
                o.x = (short)f2bf(acc[i][jj][0] + bv);
                o.y = (short)f2bf(acc[i][jj][1] + bv);
                o.z = (short)f2bf(acc[i][jj][2] + bv);
                o.w = (short)f2bf(acc[i][jj][3] + bv);
                *(s16x4*)(VTo + ((size_t)(bb * NH + h) * HD + jj * 16 + lr) * S_ + s) = o;
            }
        }
    }
}

// ---------------- flash attention (causal, NO-max softmax, split-K 4 waves) ----------------
// Block = 4 waves, ALL on the same 32 q-rows; wave w handles K-tiles kt ≡ w (mod 4).
// Partials are additive (no-max softmax): 2-round LDS tree reduce, wave 0 stores.
// R3: K-ONLY register pipeline (one k-tile ahead). R2's K+V pipeline spilled to
//     scratch (WRITE_SIZE 12->45 MB): bk+bv both live across the loop exceeded the
//     (256,3) ~170-reg cap. K alone (+32 regs, peak ~148) fits. V stays at the R0
//     position (after mask, before exp: ~400 cyc of cover from exp/transpose).
__global__ __launch_bounds__(256, 3) void attn_kernel(
    const u16* __restrict__ Q, const u16* __restrict__ K,
    const u16* __restrict__ VT, u16* __restrict__ CTX)
{
    const int tid = threadIdx.x;
    const int wave = tid >> 6;
    const int lane = tid & 63;
    const int lr = lane & 15, quad = lane >> 4;
    const int xcd = blockIdx.x & 7;
    const int idx = blockIdx.x >> 3;            // 0..383
    const int bh  = xcd * 6 + (idx % 6);
    const int qw  = 63 - (idx / 6);             // longest q-chunks first
    const int q0  = qw * 32;
    const u16* Qb = Q  + (size_t)bh * S_ * HD;
    const u16* Kb = K  + (size_t)bh * S_ * HD;
    const u16* Vb = VT + (size_t)bh * HD * S_;

    // union: per-wave score transpose buf (4*16*68 floats) | reduction buf (2*64*44)
    __shared__ __align__(16) float smem[2 * 64 * 44];   // 5632 floats = 22528 B
    float* pbuf = smem + wave * (16 * 68);

    bf16x8 aq[2][2];
    #pragma unroll
    for (int mi = 0; mi < 2; ++mi)
        #pragma unroll
        for (int kk = 0; kk < 2; ++kk)
            aq[mi][kk] = *(const bf16x8*)(Qb + (size_t)(q0 + mi * 16 + lr) * HD + kk * 32 + quad * 8);

    f32x4 o[2][4] = {};
    f32x4 lacc[2] = {};
    bf16x8 ones;
    #pragma unroll
    for (int j = 0; j < 8; ++j) ones[j] = (short)0x3F80;   // bf16 1.0

    const int ktmax = (q0 + 31) >> 6;

    // -------- pipelined K fragments (tile kt in flight); unconditional prologue --------
    // wave<<6 <= 192, always in-bounds; waves with wave > ktmax never enter the loop.
    bf16x8 bk[4][2];
    {
        const int k0 = wave << 6;
        #pragma unroll
        for (int nt = 0; nt < 4; ++nt)
            #pragma unroll
            for (int kk = 0; kk < 2; ++kk)
                bk[nt][kk] = *(const bf16x8*)(Kb + (size_t)(k0 + nt * 16 + lr) * HD + kk * 32 + quad * 8);
    }

    for (int kt = wave; kt <= ktmax; kt += 4) {
        const int k0 = kt << 6;
        const int kn = k0 + 256;                 // (kt+4)<<6
        const bool more = (kt + 4 <= ktmax);     // wave-uniform

        f32x4 sc[2][4];
        #pragma unroll
        for (int mi = 0; mi < 2; ++mi)
            #pragma unroll
            for (int nt = 0; nt < 4; ++nt) {
                f32x4 z = {0.f, 0.f, 0.f, 0.f};
                z = __builtin_amdgcn_mfma_f32_16x16x32_bf16(aq[mi][0], bk[nt][0], z, 0, 0, 0);
                z = __builtin_amdgcn_mfma_f32_16x16x32_bf16(aq[mi][1], bk[nt][1], z, 0, 0, 0);
                sc[mi][nt] = z;
            }

        // prefetch NEXT tile's K into the same regs (WAR after QK issue) —
        // exp+transpose+PV (~full tile) to land before next-iter QK consumes it
        if (more) {
            #pragma unroll
            for (int nt = 0; nt < 4; ++nt)
                #pragma unroll
                for (int kk = 0; kk < 2; ++kk)
                    bk[nt][kk] = *(const bf16x8*)(Kb + (size_t)(kn + nt * 16 + lr) * HD + kk * 32 + quad * 8);
        }

        if (kt == ktmax) {   // diagonal tile: causal mask (exp2(-inf) = 0)
            #pragma unroll
            for (int mi = 0; mi < 2; ++mi)
                #pragma unroll
                for (int nt = 0; nt < 4; ++nt)
                    #pragma unroll
                    for (int r = 0; r < 4; ++r) {
                        int row = q0 + mi * 16 + quad * 4 + r;
                        int col = k0 + nt * 16 + lr;
                        if (col > row) sc[mi][nt][r] = -INFINITY;
                    }
        }

        // V loads here (R0 position): needed only at PV, ~300 cyc away behind exp/transpose
        bf16x8 bv[4][2];
        #pragma unroll
        for (int nv = 0; nv < 4; ++nv)
            #pragma unroll
            for (int c = 0; c < 2; ++c)
                bv[nv][c] = *(const bf16x8*)(Vb + (size_t)(nv * 16 + lr) * S_ + k0 + c * 32 + quad * 8);

        // exp in C-layout; Q pre-scaled by scale*log2e
        #pragma unroll
        for (int mi = 0; mi < 2; ++mi)
            #pragma unroll
            for (int nt = 0; nt < 4; ++nt)
                #pragma unroll
                for (int r = 0; r < 4; ++r)
                    sc[mi][nt][r] = exp2f(sc[mi][nt][r]);

        // C-layout -> A-layout via per-wave LDS (wave-synchronous), mi sequential to halve LDS
        bf16x8 pa[2][2];
        #pragma unroll
        for (int mi = 0; mi < 2; ++mi) {
            #pragma unroll
            for (int r = 0; r < 4; ++r) {
                float* bp = &pbuf[(quad * 4 + r) * 68 + lr];
                bp[0]  = sc[mi][0][r];
                bp[16] = sc[mi][1][r];
                bp[32] = sc[mi][2][r];
                bp[48] = sc[mi][3][r];
            }
            #pragma unroll
            for (int c = 0; c < 2; ++c) {
                const float* rp = &pbuf[lr * 68 + c * 32 + quad * 8];
                u32x4 P;
                #pragma unroll
                for (int p = 0; p < 4; ++p)
                    P[p] = pk2(rp[2 * p], rp[2 * p + 1]);
                pa[mi][c] = __builtin_bit_cast(bf16x8, P);
            }
        }

        #pragma unroll
        for (int mi = 0; mi < 2; ++mi) {
            lacc[mi] = __builtin_amdgcn_mfma_f32_16x16x32_bf16(pa[mi][0], ones, lacc[mi], 0, 0, 0);
            lacc[mi] = __builtin_amdgcn_mfma_f32_16x16x32_bf16(pa[mi][1], ones, lacc[mi], 0, 0, 0);
            #pragma unroll
            for (int nv = 0; nv < 4; ++nv) {
                o[mi][nv] = __builtin_amdgcn_mfma_f32_16x16x32_bf16(pa[mi][0], bv[nv][0], o[mi][nv], 0, 0, 0);
                o[mi][nv] = __builtin_amdgcn_mfma_f32_16x16x32_bf16(pa[mi][1], bv[nv][1], o[mi][nv], 0, 0, 0);
            }
        }
    }

    // -------- cross-wave reduction (partials are additive) --------
    __syncthreads();
    float* red = smem;          // [2][64][44]
    if (wave >= 2) {
        float* rp = red + (wave - 2) * (64 * 44) + lane * 44;
        #pragma unroll
        for (int mi = 0; mi < 2; ++mi) {
            #pragma unroll
            for (int nv = 0; nv < 4; ++nv)
                *(f32x4*)(rp + (mi * 4 + nv) * 4) = o[mi][nv];
            *(f32x4*)(rp + 32 + mi * 4) = lacc[mi];
        }
    }
    __syncthreads();
    if (wave < 2) {
        const float* rp = red + wave * (64 * 44) + lane * 44;
        #pragma unroll
        for (int mi = 0; mi < 2; ++mi) {
            #pragma unroll
            for (int nv = 0; nv < 4; ++nv)
                o[mi][nv] += *(const f32x4*)(rp + (mi * 4 + nv) * 4);
            lacc[mi] += *(const f32x4*)(rp + 32 + mi * 4);
        }
    }
    __syncthreads();
    if (wave == 1) {
        float* rp = red + lane * 44;
        #pragma unroll
        for (int mi = 0; mi < 2; ++mi) {
            #pragma unroll
            for (int nv = 0; nv < 4; ++nv)
                *(f32x4*)(rp + (mi * 4 + nv) * 4) = o[mi][nv];
            *(f32x4*)(rp + 32 + mi * 4) = lacc[mi];
        }
    }
    __syncthreads();
    if (wave == 0) {
        const float* rp = red + lane * 44;
        #pragma unroll
        for (int mi = 0; mi < 2; ++mi) {
            #pragma unroll
            for (int nv = 0; nv < 4; ++nv)
                o[mi][nv] += *(const f32x4*)(rp + (mi * 4 + nv) * 4);
            lacc[mi] += *(const f32x4*)(rp + 32 + mi * 4);
        }
        const int bb = bh / NH, h = bh % NH;
        #pragma unroll
        for (int mi = 0; mi < 2; ++mi) {
            f32x4 inv;
            #pragma unroll
            for (int r = 0; r < 4; ++r) inv[r] = 1.0f / lacc[mi][r];
            #pragma unroll
            for (int nv = 0; nv < 4; ++nv)
                #pragma unroll
                for (int r = 0; r < 4; ++r)
                    CTX[(size_t)(bb * S_ + q0 + mi * 16 + quad * 4 + r) * DM + h * HD + nv * 16 + lr]
                        = f2bf(o[mi][nv][r] * inv[r]);
        }
    }
}

// ---------------- output projection GEMM (LDS-staged, fp32 out) ----------------
__global__ __launch_bounds__(256) void o_gemm(
    const u16* __restrict__ X, const u16* __restrict__ W,
    const float* __restrict__ bias, float* __restrict__ Out)
{
    __shared__ __align__(16) u16 As[128 * 32];
    __shared__ __align__(16) u16 Bs[128 * 32];

    const int mt = blockIdx.x / 6, nt = blockIdx.x % 6;
    const int lane = threadIdx.x & 63;
    const int lr = lane & 15, quad = lane >> 4;
    const int wave = threadIdx.x >> 6;
    const int m0 = mt * 128 + (wave & 1) * 64;
    const int n0 = nt * 128 + (wave >> 1) * 64;

    f32x4 acc[4][4] = {};
    gemm_core_128(X, W, mt * 128, nt * 128, As, Bs, acc);

    #pragma unroll
    for (int jj = 0; jj < 4; ++jj) {
        float bv = bias[n0 + jj * 16 + lr];
        #pragma unroll
        for (int i = 0; i < 4; ++i)
            #pragma unroll
            for (int r = 0; r < 4; ++r)
                Out[(size_t)(m0 + i * 16 + quad * 4 + r) * DM + n0 + jj * 16 + lr] = acc[i][jj][r] + bv;
    }
}

extern "C" void kernel_launch(void* const* d_in, const int* in_sizes, int n_in,
                              void* d_out, int out_size, void* d_ws, size_t ws_size,
                              hipStream_t stream) {
    const float* q  = (const float*)d_in[0];
    const float* k  = (const float*)d_in[1];
    const float* v  = (const float*)d_in[2];
    const float* WQ = (const float*)d_in[3];
    const float* bQ = (const float*)d_in[4];
    const float* WK = (const float*)d_in[5];
    const float* bK = (const float*)d_in[6];
    const float* WV = (const float*)d_in[7];
    const float* bV = (const float*)d_in[8];
    const float* WO = (const float*)d_in[9];
    const float* bO = (const float*)d_in[10];

    char* ws = (char*)d_ws;
    const size_t SZ_X = (size_t)MT * DM * 2;   // 12,582,912 B
    const size_t SZ_W = (size_t)DM * DM * 2;   //  1,179,648 B
    u16* Xq = (u16*)(ws);
    u16* Xk = (u16*)(ws + SZ_X);
    u16* Xv = (u16*)(ws + 2 * SZ_X);
    u16* Wq = (u16*)(ws + 3 * SZ_X);
    u16* Wk = (u16*)(ws + 3 * SZ_X + SZ_W);
    u16* Wv = (u16*)(ws + 3 * SZ_X + 2 * SZ_W);
    u16* Wo = (u16*)(ws + 3 * SZ_X + 3 * SZ_W);
    u16* Qh  = (u16*)(ws + 3 * SZ_X + 4 * SZ_W);
    u16* Kh  = (u16*)(ws + 4 * SZ_X + 4 * SZ_W);
    u16* VTh = (u16*)(ws + 5 * SZ_X + 4 * SZ_W);
    u16* CTX = Xq;   // Xq dead after qkv_gemm; reuse

    const int nX = MT * DM;    // 6,291,456
    const int nW = DM * DM;    //   589,824
    cvt3_kernel<<<3 * (nX / 1024), 256, 0, stream>>>(q, k, v, Xq, Xk, Xv, nX / 1024);
    cvt4_kernel<<<4 * (nW / 1024), 256, 0, stream>>>(WQ, WK, WV, WO, Wq, Wk, Wv, Wo, nW / 1024);

    qkv_gemm<<<1152, 256, 0, stream>>>(Xq, Xk, Xv, Wq, Wk, Wv, bQ, bK, bV, Qh, Kh, VTh);
    attn_kernel<<<3072, 256, 0, stream>>>(Qh, Kh, VTh, CTX);
    o_gemm<<<384, 256, 0, stream>>>(CTX, Wo, bO, (float*)d_out);
}

// Round 4
// 316.181 us; speedup vs baseline: 1.0762x; 1.0762x over previous
//
#include <hip/hip_runtime.h>
#include <hip/hip_bf16.h>

#define DM 768
#define NH 12
#define HD 64
#define B_ 4
#define S_ 2048
#define MT (B_*S_)   // 8192 rows

typedef unsigned short u16;
typedef __attribute__((ext_vector_type(8))) short bf16x8;
typedef __attribute__((ext_vector_type(4))) float f32x4;
typedef __attribute__((ext_vector_type(4))) short s16x4;
typedef __attribute__((ext_vector_type(4))) unsigned u32x4;

__device__ __forceinline__ u16 f2bf(float f) {
    union { float f; unsigned u; } x; x.f = f;
    unsigned r = x.u + 0x7fffu + ((x.u >> 16) & 1u);   // RNE
    return (u16)(r >> 16);
}

__device__ __forceinline__ unsigned pk2(float a, float b) {
    union { __hip_bfloat162 h; unsigned u; } cv;
    cv.h = __float22bfloat162_rn(float2{a, b});
    return cv.u;
}

// gfx950 cross-lane half-swaps (both outputs live via "+v","+v"):
// v_permlane32_swap_b32: dst lanes 32-63 <-> src lanes 0-31
__device__ __forceinline__ void swap32(unsigned& a, unsigned& b) {
    asm volatile("v_permlane32_swap_b32 %0, %1" : "+v"(a), "+v"(b));
}
// v_permlane16_swap_b32: dst lanes 16-31 <-> src lanes 0-15; dst 48-63 <-> src 32-47
__device__ __forceinline__ void swap16(unsigned& a, unsigned& b) {
    asm volatile("v_permlane16_swap_b32 %0, %1" : "+v"(a), "+v"(b));
}

#define GLD_LDS(gp, lp) \
    __builtin_amdgcn_global_load_lds( \
        (const __attribute__((address_space(1))) void*)(gp), \
        (__attribute__((address_space(3))) void*)(lp), 16, 0, 0)

// ---------------- fused fp32 -> bf16 conversions ----------------
__global__ void cvt3_kernel(const float* __restrict__ s0, const float* __restrict__ s1,
                            const float* __restrict__ s2,
                            u16* __restrict__ d0, u16* __restrict__ d1, u16* __restrict__ d2,
                            int blocksPer) {
    int sel = blockIdx.x / blocksPer;           // uniform per block
    int rel = blockIdx.x % blocksPer;
    const float* s = (sel == 0) ? s0 : (sel == 1) ? s1 : s2;
    u16* d = (sel == 0) ? d0 : (sel == 1) ? d1 : d2;
    int i = (rel * 256 + threadIdx.x) * 4;
    float4 v = *(const float4*)(s + i);
    s16x4 o;
    o.x = (short)f2bf(v.x); o.y = (short)f2bf(v.y);
    o.z = (short)f2bf(v.z); o.w = (short)f2bf(v.w);
    *(s16x4*)(d + i) = o;
}

__global__ void cvt4_kernel(const float* __restrict__ s0, const float* __restrict__ s1,
                            const float* __restrict__ s2, const float* __restrict__ s3,
                            u16* __restrict__ d0, u16* __restrict__ d1,
                            u16* __restrict__ d2, u16* __restrict__ d3,
                            int blocksPer) {
    int sel = blockIdx.x / blocksPer;
    int rel = blockIdx.x % blocksPer;
    const float* s = (sel == 0) ? s0 : (sel == 1) ? s1 : (sel == 2) ? s2 : s3;
    u16* d = (sel == 0) ? d0 : (sel == 1) ? d1 : (sel == 2) ? d2 : d3;
    int i = (rel * 256 + threadIdx.x) * 4;
    float4 v = *(const float4*)(s + i);
    s16x4 o;
    o.x = (short)f2bf(v.x); o.y = (short)f2bf(v.y);
    o.z = (short)f2bf(v.z); o.w = (short)f2bf(v.w);
    *(s16x4*)(d + i) = o;
}

// ---------------- shared 128x128-tile MFMA core (m97 structure) ----------------
__device__ __forceinline__ void gemm_core_128(
    const u16* __restrict__ A, const u16* __restrict__ B,
    int m0, int n0, u16* As, u16* Bs, f32x4 acc[4][4])
{
    const int tid = threadIdx.x;
    const int lane = tid & 63;
    const int lr = lane & 15, quad = lane >> 4;
    const int wave = tid >> 6;
    const int wm = (wave & 1) * 64, wn = (wave >> 1) * 64;

    for (int ks = 0; ks < 24; ++ks) {
        #pragma unroll
        for (int r = 0; r < 2; ++r) {
            int idx = r * 256 + tid;
            int row = idx >> 2, col = (idx & 3) * 8;
            GLD_LDS(A + (size_t)(m0 + row) * DM + ks * 32 + col, As + idx * 8);
            GLD_LDS(B + (size_t)(n0 + row) * DM + ks * 32 + col, Bs + idx * 8);
        }
        __syncthreads();
        bf16x8 a[4], b[4];
        #pragma unroll
        for (int i = 0; i < 4; ++i) a[i] = *(const bf16x8*)(As + (wm + i * 16 + lr) * 32 + quad * 8);
        #pragma unroll
        for (int j = 0; j < 4; ++j) b[j] = *(const bf16x8*)(Bs + (wn + j * 16 + lr) * 32 + quad * 8);
        #pragma unroll
        for (int i = 0; i < 4; ++i)
            #pragma unroll
            for (int j = 0; j < 4; ++j)
                acc[i][j] = __builtin_amdgcn_mfma_f32_16x16x32_bf16(a[i], b[j], acc[i][j], 0, 0, 0);
        __syncthreads();
    }
}

// ---------------- fused QKV projection GEMM (LDS-staged) ----------------
__global__ __launch_bounds__(256) void qkv_gemm(
    const u16* __restrict__ Xq, const u16* __restrict__ Xk, const u16* __restrict__ Xv,
    const u16* __restrict__ Wq, const u16* __restrict__ Wk, const u16* __restrict__ Wv,
    const float* __restrict__ bQ, const float* __restrict__ bK, const float* __restrict__ bV,
    u16* __restrict__ Qo, u16* __restrict__ Ko, u16* __restrict__ VTo)
{
    __shared__ __align__(16) u16 As[128 * 32];
    __shared__ __align__(16) u16 Bs[128 * 32];

    const int mat = blockIdx.x / 384;           // uniform per block
    const int t   = blockIdx.x % 384;
    const int mt  = t / 6, nt = t % 6;
    const u16* X = (mat == 0) ? Xq : (mat == 1 ? Xk : Xv);
    const u16* W = (mat == 0) ? Wq : (mat == 1 ? Wk : Wv);
    const float* bias = (mat == 0) ? bQ : (mat == 1 ? bK : bV);

    const int lane = threadIdx.x & 63;
    const int lr = lane & 15, quad = lane >> 4;
    const int wave = threadIdx.x >> 6;
    const int m0 = mt * 128 + (wave & 1) * 64;
    const int n0 = nt * 128 + (wave >> 1) * 64;

    f32x4 acc[4][4] = {};
    gemm_core_128(X, W, mt * 128, nt * 128, As, Bs, acc);

    const int bb = m0 / S_, s0 = m0 % S_, h = n0 / HD;
    if (mat < 2) {
        u16* O = (mat == 0) ? Qo : Ko;
        const float qs = (mat == 0) ? 0.18033688011112042f : 1.0f;  // (1/8)*log2(e)
        #pragma unroll
        for (int jj = 0; jj < 4; ++jj) {
            float bv = bias[n0 + jj * 16 + lr];
            #pragma unroll
            for (int i = 0; i < 4; ++i)
                #pragma unroll
                for (int r = 0; r < 4; ++r) {
                    int s = s0 + i * 16 + quad * 4 + r;
                    O[((size_t)(bb * NH + h) * S_ + s) * HD + jj * 16 + lr] = f2bf((acc[i][jj][r] + bv) * qs);
                }
        }
    } else {
        #pragma unroll
        for (int jj = 0; jj < 4; ++jj) {
            float bv = bias[n0 + jj * 16 + lr];
            #pragma unroll
            for (int i = 0; i < 4; ++i) {
                int s = s0 + i * 16 + quad * 4;
                s16x4 o;
                o.x = (short)f2bf(acc[i][jj][0] + bv);
                o.y = (short)f2bf(acc[i][jj][1] + bv);
                o.z = (short)f2bf(acc[i][jj][2] + bv);
                o.w = (short)f2bf(acc[i][jj][3] + bv);
                *(s16x4*)(VTo + ((size_t)(bb * NH + h) * HD + jj * 16 + lr) * S_ + s) = o;
            }
        }
    }
}

// ---------------- flash attention (causal, NO-max softmax, split-K 4 waves) ----------------
// Block = 4 waves, ALL on the same 32 q-rows; wave w handles K-tiles kt ≡ w (mod 4).
// Partials are additive (no-max softmax): 2-round LDS tree reduce, wave 0 stores.
// R4 (T12): swapped QK^T — sT = mfma(K_frag, Q_frag) so scores land TRANSPOSED:
//   lane(lr,quad) holds P[q=lr][key=16t+quad*4+r].  The C->A layout transpose is then
//   pure-register: per 32-key chunk, pk2 pairs + permlane32_swap + permlane16_swap
//   yield the PV A-frag words directly ([a0,a1,a2,a3],[b0..] -> [a0,a2,b0,b2],[a1,a3,b1,b3]).
//   Replaces the per-tile LDS transpose (32 ds_write + 32 ds_read + waits). No cross-loop
//   prefetch arrays (R2/R3 both spilled to scratch); loads stay at R0 positions.
__global__ __launch_bounds__(256, 3) void attn_kernel(
    const u16* __restrict__ Q, const u16* __restrict__ K,
    const u16* __restrict__ VT, u16* __restrict__ CTX)
{
    const int tid = threadIdx.x;
    const int wave = tid >> 6;
    const int lane = tid & 63;
    const int lr = lane & 15, quad = lane >> 4;
    const int xcd = blockIdx.x & 7;
    const int idx = blockIdx.x >> 3;            // 0..383
    const int bh  = xcd * 6 + (idx % 6);
    const int qw  = 63 - (idx / 6);             // longest q-chunks first
    const int q0  = qw * 32;
    const u16* Qb = Q  + (size_t)bh * S_ * HD;
    const u16* Kb = K  + (size_t)bh * S_ * HD;
    const u16* Vb = VT + (size_t)bh * HD * S_;

    // LDS only for the cross-wave reduction now
    __shared__ __align__(16) float smem[2 * 64 * 44];   // 5632 floats = 22528 B

    bf16x8 aq[2][2];
    #pragma unroll
    for (int mi = 0; mi < 2; ++mi)
        #pragma unroll
        for (int kk = 0; kk < 2; ++kk)
            aq[mi][kk] = *(const bf16x8*)(Qb + (size_t)(q0 + mi * 16 + lr) * HD + kk * 32 + quad * 8);

    f32x4 o[2][4] = {};
    f32x4 lacc[2] = {};
    bf16x8 ones;
    #pragma unroll
    for (int j = 0; j < 8; ++j) ones[j] = (short)0x3F80;   // bf16 1.0

    const int ktmax = (q0 + 31) >> 6;

    for (int kt = wave; kt <= ktmax; kt += 4) {
        const int k0 = kt << 6;

        bf16x8 bk[4][2];
        #pragma unroll
        for (int nt = 0; nt < 4; ++nt)
            #pragma unroll
            for (int kk = 0; kk < 2; ++kk)
                bk[nt][kk] = *(const bf16x8*)(Kb + (size_t)(k0 + nt * 16 + lr) * HD + kk * 32 + quad * 8);

        // swapped QK^T: sT[mi][t] in C-layout = P^T — lane holds q=lr, key=16t+quad*4+r
        f32x4 sT[2][4];
        #pragma unroll
        for (int mi = 0; mi < 2; ++mi)
            #pragma unroll
            for (int t = 0; t < 4; ++t) {
                f32x4 z = {0.f, 0.f, 0.f, 0.f};
                z = __builtin_amdgcn_mfma_f32_16x16x32_bf16(bk[t][0], aq[mi][0], z, 0, 0, 0);
                z = __builtin_amdgcn_mfma_f32_16x16x32_bf16(bk[t][1], aq[mi][1], z, 0, 0, 0);
                sT[mi][t] = z;
            }

        if (kt == ktmax) {   // diagonal tile: causal mask (exp2(-inf) = 0); swapped indices
            #pragma unroll
            for (int mi = 0; mi < 2; ++mi) {
                int qrow = q0 + mi * 16 + lr;
                #pragma unroll
                for (int t = 0; t < 4; ++t)
                    #pragma unroll
                    for (int r = 0; r < 4; ++r) {
                        int key = k0 + t * 16 + quad * 4 + r;
                        if (key > qrow) sT[mi][t][r] = -INFINITY;
                    }
            }
        }

        // V loads here: needed only at PV, ~2x(exp+pack+permlane) away
        bf16x8 bv[4][2];
        #pragma unroll
        for (int nv = 0; nv < 4; ++nv)
            #pragma unroll
            for (int c = 0; c < 2; ++c)
                bv[nv][c] = *(const bf16x8*)(Vb + (size_t)(nv * 16 + lr) * S_ + k0 + c * 32 + quad * 8);

        // exp (Q pre-scaled by scale*log2e) + in-register transpose to A-layout
        bf16x8 pa[2][2];
        #pragma unroll
        for (int mi = 0; mi < 2; ++mi) {
            #pragma unroll
            for (int t = 0; t < 4; ++t)
                #pragma unroll
                for (int r = 0; r < 4; ++r)
                    sT[mi][t][r] = exp2f(sT[mi][t][r]);

            #pragma unroll
            for (int c = 0; c < 2; ++c) {
                // chunks 2c (A) and 2c+1 (B), packed to bf16 pairs
                unsigned u00 = pk2(sT[mi][2 * c + 0][0], sT[mi][2 * c + 0][1]);  // a_q = P[4q+0..1]
                unsigned u01 = pk2(sT[mi][2 * c + 0][2], sT[mi][2 * c + 0][3]);  // a'_q = P[4q+2..3]
                unsigned u10 = pk2(sT[mi][2 * c + 1][0], sT[mi][2 * c + 1][1]);  // b_q
                unsigned u11 = pk2(sT[mi][2 * c + 1][2], sT[mi][2 * c + 1][3]);  // b'_q
                // [a0,a1,a2,a3],[b0,b1,b2,b3] -> [a0,a2,b0,b2],[a1,a3,b1,b3]
                swap32(u00, u10); swap16(u00, u10);   // u00=w0 (k 8q+0..1), u10=w2 (k 8q+4..5)
                swap32(u01, u11); swap16(u01, u11);   // u01=w1 (k 8q+2..3), u11=w3 (k 8q+6..7)
                u32x4 P = {u00, u01, u10, u11};
                pa[mi][c] = __builtin_bit_cast(bf16x8, P);
            }
        }

        #pragma unroll
        for (int mi = 0; mi < 2; ++mi) {
            lacc[mi] = __builtin_amdgcn_mfma_f32_16x16x32_bf16(pa[mi][0], ones, lacc[mi], 0, 0, 0);
            lacc[mi] = __builtin_amdgcn_mfma_f32_16x16x32_bf16(pa[mi][1], ones, lacc[mi], 0, 0, 0);
            #pragma unroll
            for (int nv = 0; nv < 4; ++nv) {
                o[mi][nv] = __builtin_amdgcn_mfma_f32_16x16x32_bf16(pa[mi][0], bv[nv][0], o[mi][nv], 0, 0, 0);
                o[mi][nv] = __builtin_amdgcn_mfma_f32_16x16x32_bf16(pa[mi][1], bv[nv][1], o[mi][nv], 0, 0, 0);
            }
        }
    }

    // -------- cross-wave reduction (partials are additive) --------
    __syncthreads();
    float* red = smem;          // [2][64][44]
    if (wave >= 2) {
        float* rp = red + (wave - 2) * (64 * 44) + lane * 44;
        #pragma unroll
        for (int mi = 0; mi < 2; ++mi) {
            #pragma unroll
            for (int nv = 0; nv < 4; ++nv)
                *(f32x4*)(rp + (mi * 4 + nv) * 4) = o[mi][nv];
            *(f32x4*)(rp + 32 + mi * 4) = lacc[mi];
        }
    }
    __syncthreads();
    if (wave < 2) {
        const float* rp = red + wave * (64 * 44) + lane * 44;
        #pragma unroll
        for (int mi = 0; mi < 2; ++mi) {
            #pragma unroll
            for (int nv = 0; nv < 4; ++nv)
                o[mi][nv] += *(const f32x4*)(rp + (mi * 4 + nv) * 4);
            lacc[mi] += *(const f32x4*)(rp + 32 + mi * 4);
        }
    }
    __syncthreads();
    if (wave == 1) {
        float* rp = red + lane * 44;
        #pragma unroll
        for (int mi = 0; mi < 2; ++mi) {
            #pragma unroll
            for (int nv = 0; nv < 4; ++nv)
                *(f32x4*)(rp + (mi * 4 + nv) * 4) = o[mi][nv];
            *(f32x4*)(rp + 32 + mi * 4) = lacc[mi];
        }
    }
    __syncthreads();
    if (wave == 0) {
        const float* rp = red + lane * 44;
        #pragma unroll
        for (int mi = 0; mi < 2; ++mi) {
            #pragma unroll
            for (int nv = 0; nv < 4; ++nv)
                o[mi][nv] += *(const f32x4*)(rp + (mi * 4 + nv) * 4);
            lacc[mi] += *(const f32x4*)(rp + 32 + mi * 4);
        }
        const int bb = bh / NH, h = bh % NH;
        #pragma unroll
        for (int mi = 0; mi < 2; ++mi) {
            f32x4 inv;
            #pragma unroll
            for (int r = 0; r < 4; ++r) inv[r] = 1.0f / lacc[mi][r];
            #pragma unroll
            for (int nv = 0; nv < 4; ++nv)
                #pragma unroll
                for (int r = 0; r < 4; ++r)
                    CTX[(size_t)(bb * S_ + q0 + mi * 16 + quad * 4 + r) * DM + h * HD + nv * 16 + lr]
                        = f2bf(o[mi][nv][r] * inv[r]);
        }
    }
}

// ---------------- output projection GEMM (LDS-staged, fp32 out) ----------------
__global__ __launch_bounds__(256) void o_gemm(
    const u16* __restrict__ X, const u16* __restrict__ W,
    const float* __restrict__ bias, float* __restrict__ Out)
{
    __shared__ __align__(16) u16 As[128 * 32];
    __shared__ __align__(16) u16 Bs[128 * 32];

    const int mt = blockIdx.x / 6, nt = blockIdx.x % 6;
    const int lane = threadIdx.x & 63;
    const int lr = lane & 15, quad = lane >> 4;
    const int wave = threadIdx.x >> 6;
    const int m0 = mt * 128 + (wave & 1) * 64;
    const int n0 = nt * 128 + (wave >> 1) * 64;

    f32x4 acc[4][4] = {};
    gemm_core_128(X, W, mt * 128, nt * 128, As, Bs, acc);

    #pragma unroll
    for (int jj = 0; jj < 4; ++jj) {
        float bv = bias[n0 + jj * 16 + lr];
        #pragma unroll
        for (int i = 0; i < 4; ++i)
            #pragma unroll
            for (int r = 0; r < 4; ++r)
                Out[(size_t)(m0 + i * 16 + quad * 4 + r) * DM + n0 + jj * 16 + lr] = acc[i][jj][r] + bv;
    }
}

extern "C" void kernel_launch(void* const* d_in, const int* in_sizes, int n_in,
                              void* d_out, int out_size, void* d_ws, size_t ws_size,
                              hipStream_t stream) {
    const float* q  = (const float*)d_in[0];
    const float* k  = (const float*)d_in[1];
    const float* v  = (const float*)d_in[2];
    const float* WQ = (const float*)d_in[3];
    const float* bQ = (const float*)d_in[4];
    const float* WK = (const float*)d_in[5];
    const float* bK = (const float*)d_in[6];
    const float* WV = (const float*)d_in[7];
    const float* bV = (const float*)d_in[8];
    const float* WO = (const float*)d_in[9];
    const float* bO = (const float*)d_in[10];

    char* ws = (char*)d_ws;
    const size_t SZ_X = (size_t)MT * DM * 2;   // 12,582,912 B
    const size_t SZ_W = (size_t)DM * DM * 2;   //  1,179,648 B
    u16* Xq = (u16*)(ws);
    u16* Xk = (u16*)(ws + SZ_X);
    u16* Xv = (u16*)(ws + 2 * SZ_X);
    u16* Wq = (u16*)(ws + 3 * SZ_X);
    u16* Wk = (u16*)(ws + 3 * SZ_X + SZ_W);
    u16* Wv = (u16*)(ws + 3 * SZ_X + 2 * SZ_W);
    u16* Wo = (u16*)(ws + 3 * SZ_X + 3 * SZ_W);
    u16* Qh  = (u16*)(ws + 3 * SZ_X + 4 * SZ_W);
    u16* Kh  = (u16*)(ws + 4 * SZ_X + 4 * SZ_W);
    u16* VTh = (u16*)(ws + 5 * SZ_X + 4 * SZ_W);
    u16* CTX = Xq;   // Xq dead after qkv_gemm; reuse

    const int nX = MT * DM;    // 6,291,456
    const int nW = DM * DM;    //   589,824
    cvt3_kernel<<<3 * (nX / 1024), 256, 0, stream>>>(q, k, v, Xq, Xk, Xv, nX / 1024);
    cvt4_kernel<<<4 * (nW / 1024), 256, 0, stream>>>(WQ, WK, WV, WO, Wq, Wk, Wv, Wo, nW / 1024);

    qkv_gemm<<<1152, 256, 0, stream>>>(Xq, Xk, Xv, Wq, Wk, Wv, bQ, bK, bV, Qh, Kh, VTh);
    attn_kernel<<<3072, 256, 0, stream>>>(Qh, Kh, VTh, CTX);
    o_gemm<<<384, 256, 0, stream>>>(CTX, Wo, bO, (float*)d_out);
}

// Round 5
// 274.881 us; speedup vs baseline: 1.2379x; 1.1502x over previous
//
#include <hip/hip_runtime.h>
#include <hip/hip_bf16.h>

#define DM 768
#define NH 12
#define HD 64
#define B_ 4
#define S_ 2048
#define MT (B_*S_)   // 8192 rows

typedef unsigned short u16;
typedef __attribute__((ext_vector_type(8))) short bf16x8;
typedef __attribute__((ext_vector_type(4))) float f32x4;
typedef __attribute__((ext_vector_type(4))) short s16x4;
typedef __attribute__((ext_vector_type(4))) unsigned u32x4;

__device__ __forceinline__ u16 f2bf(float f) {
    union { float f; unsigned u; } x; x.f = f;
    unsigned r = x.u + 0x7fffu + ((x.u >> 16) & 1u);   // RNE
    return (u16)(r >> 16);
}

__device__ __forceinline__ unsigned pk2(float a, float b) {
    union { __hip_bfloat162 h; unsigned u; } cv;
    cv.h = __float22bfloat162_rn(float2{a, b});
    return cv.u;
}

// gfx950 cross-lane half-swaps (both outputs live via "+v","+v"):
__device__ __forceinline__ void swap32(unsigned& a, unsigned& b) {
    asm volatile("v_permlane32_swap_b32 %0, %1" : "+v"(a), "+v"(b));
}
__device__ __forceinline__ void swap16(unsigned& a, unsigned& b) {
    asm volatile("v_permlane16_swap_b32 %0, %1" : "+v"(a), "+v"(b));
}

#define GLD_LDS(gp, lp) \
    __builtin_amdgcn_global_load_lds( \
        (const __attribute__((address_space(1))) void*)(gp), \
        (__attribute__((address_space(3))) void*)(lp), 16, 0, 0)

// ---------------- fused fp32 -> bf16 conversions ----------------
__global__ void cvt3_kernel(const float* __restrict__ s0, const float* __restrict__ s1,
                            const float* __restrict__ s2,
                            u16* __restrict__ d0, u16* __restrict__ d1, u16* __restrict__ d2,
                            int blocksPer) {
    int sel = blockIdx.x / blocksPer;           // uniform per block
    int rel = blockIdx.x % blocksPer;
    const float* s = (sel == 0) ? s0 : (sel == 1) ? s1 : s2;
    u16* d = (sel == 0) ? d0 : (sel == 1) ? d1 : d2;
    int i = (rel * 256 + threadIdx.x) * 4;
    float4 v = *(const float4*)(s + i);
    s16x4 o;
    o.x = (short)f2bf(v.x); o.y = (short)f2bf(v.y);
    o.z = (short)f2bf(v.z); o.w = (short)f2bf(v.w);
    *(s16x4*)(d + i) = o;
}

__global__ void cvt4_kernel(const float* __restrict__ s0, const float* __restrict__ s1,
                            const float* __restrict__ s2, const float* __restrict__ s3,
                            u16* __restrict__ d0, u16* __restrict__ d1,
                            u16* __restrict__ d2, u16* __restrict__ d3,
                            int blocksPer) {
    int sel = blockIdx.x / blocksPer;
    int rel = blockIdx.x % blocksPer;
    const float* s = (sel == 0) ? s0 : (sel == 1) ? s1 : (sel == 2) ? s2 : s3;
    u16* d = (sel == 0) ? d0 : (sel == 1) ? d1 : (sel == 2) ? d2 : d3;
    int i = (rel * 256 + threadIdx.x) * 4;
    float4 v = *(const float4*)(s + i);
    s16x4 o;
    o.x = (short)f2bf(v.x); o.y = (short)f2bf(v.y);
    o.z = (short)f2bf(v.z); o.w = (short)f2bf(v.w);
    *(s16x4*)(d + i) = o;
}

// ---------------- shared 128x128-tile MFMA core (m97 structure) ----------------
__device__ __forceinline__ void gemm_core_128(
    const u16* __restrict__ A, const u16* __restrict__ B,
    int m0, int n0, u16* As, u16* Bs, f32x4 acc[4][4])
{
    const int tid = threadIdx.x;
    const int lane = tid & 63;
    const int lr = lane & 15, quad = lane >> 4;
    const int wave = tid >> 6;
    const int wm = (wave & 1) * 64, wn = (wave >> 1) * 64;

    for (int ks = 0; ks < 24; ++ks) {
        #pragma unroll
        for (int r = 0; r < 2; ++r) {
            int idx = r * 256 + tid;
            int row = idx >> 2, col = (idx & 3) * 8;
            GLD_LDS(A + (size_t)(m0 + row) * DM + ks * 32 + col, As + idx * 8);
            GLD_LDS(B + (size_t)(n0 + row) * DM + ks * 32 + col, Bs + idx * 8);
        }
        __syncthreads();
        bf16x8 a[4], b[4];
        #pragma unroll
        for (int i = 0; i < 4; ++i) a[i] = *(const bf16x8*)(As + (wm + i * 16 + lr) * 32 + quad * 8);
        #pragma unroll
        for (int j = 0; j < 4; ++j) b[j] = *(const bf16x8*)(Bs + (wn + j * 16 + lr) * 32 + quad * 8);
        #pragma unroll
        for (int i = 0; i < 4; ++i)
            #pragma unroll
            for (int j = 0; j < 4; ++j)
                acc[i][j] = __builtin_amdgcn_mfma_f32_16x16x32_bf16(a[i], b[j], acc[i][j], 0, 0, 0);
        __syncthreads();
    }
}

// ---------------- fused QKV projection GEMM (LDS-staged) ----------------
__global__ __launch_bounds__(256) void qkv_gemm(
    const u16* __restrict__ Xq, const u16* __restrict__ Xk, const u16* __restrict__ Xv,
    const u16* __restrict__ Wq, const u16* __restrict__ Wk, const u16* __restrict__ Wv,
    const float* __restrict__ bQ, const float* __restrict__ bK, const float* __restrict__ bV,
    u16* __restrict__ Qo, u16* __restrict__ Ko, u16* __restrict__ VTo)
{
    __shared__ __align__(16) u16 As[128 * 32];
    __shared__ __align__(16) u16 Bs[128 * 32];

    const int mat = blockIdx.x / 384;           // uniform per block
    const int t   = blockIdx.x % 384;
    const int mt  = t / 6, nt = t % 6;
    const u16* X = (mat == 0) ? Xq : (mat == 1 ? Xk : Xv);
    const u16* W = (mat == 0) ? Wq : (mat == 1 ? Wk : Wv);
    const float* bias = (mat == 0) ? bQ : (mat == 1 ? bK : bV);

    const int lane = threadIdx.x & 63;
    const int lr = lane & 15, quad = lane >> 4;
    const int wave = threadIdx.x >> 6;
    const int m0 = mt * 128 + (wave & 1) * 64;
    const int n0 = nt * 128 + (wave >> 1) * 64;

    f32x4 acc[4][4] = {};
    gemm_core_128(X, W, mt * 128, nt * 128, As, Bs, acc);

    const int bb = m0 / S_, s0 = m0 % S_, h = n0 / HD;
    if (mat < 2) {
        u16* O = (mat == 0) ? Qo : Ko;
        const float qs = (mat == 0) ? 0.18033688011112042f : 1.0f;  // (1/8)*log2(e)
        #pragma unroll
        for (int jj = 0; jj < 4; ++jj) {
            float bv = bias[n0 + jj * 16 + lr];
            #pragma unroll
            for (int i = 0; i < 4; ++i)
                #pragma unroll
                for (int r = 0; r < 4; ++r) {
                    int s = s0 + i * 16 + quad * 4 + r;
                    O[((size_t)(bb * NH + h) * S_ + s) * HD + jj * 16 + lr] = f2bf((acc[i][jj][r] + bv) * qs);
                }
        }
    } else {
        #pragma unroll
        for (int jj = 0; jj < 4; ++jj) {
            float bv = bias[n0 + jj * 16 + lr];
            #pragma unroll
            for (int i = 0; i < 4; ++i) {
                int s = s0 + i * 16 + quad * 4;
                s16x4 o;
                o.x = (short)f2bf(acc[i][jj][0] + bv);
                o.y = (short)f2bf(acc[i][jj][1] + bv);
                o.z = (short)f2bf(acc[i][jj][2] + bv);
                o.w = (short)f2bf(acc[i][jj][3] + bv);
                *(s16x4*)(VTo + ((size_t)(bb * NH + h) * HD + jj * 16 + lr) * S_ + s) = o;
            }
        }
    }
}

// ---------------- flash attention (causal, NO-max softmax) ----------------
// R5 restructure: block owns 128 q-rows (4 waves x 32); ALL waves iterate the SAME
// kt sequence 0..KT. K/V tile (64 keys) staged ONCE per block into double-buffered
// LDS via 16 coalesced 1KB global_load_lds (vs 64 scattered flat loads before):
// 4x L1/L2 traffic cut, 16x fewer memory instructions. One barrier per tile;
// staging for kt+1 issued before compute of kt (2-phase pipeline, m97 pattern).
// XOR swizzle (chunk ^= row&7) applied BOTH sides: inverse-swizzled global source
// (linear LDS dest, rule #21) + swizzled ds_read -> conflict-free b128 reads.
// Split-K reduction epilogue deleted: each wave owns its rows end-to-end.
// Swapped QK^T + permlane transpose retained from R4.
__global__ __launch_bounds__(256, 3) void attn_kernel(
    const u16* __restrict__ Q, const u16* __restrict__ K,
    const u16* __restrict__ VT, u16* __restrict__ CTX)
{
    const int tid = threadIdx.x;
    const int wave = tid >> 6;
    const int lane = tid & 63;
    const int lr = lane & 15, quad = lane >> 4;

    const int xcd = blockIdx.x & 7;
    const int i2  = blockIdx.x >> 3;            // 0..95
    const int bh  = xcd * 6 + (i2 % 6);
    const int qc  = 15 - (i2 / 6);              // longest q-chunks first
    const int Q0  = qc * 128;
    const int q0w = Q0 + wave * 32;             // this wave's 32 q-rows

    const u16* Qb = Q  + (size_t)bh * S_ * HD;
    const u16* Kb = K  + (size_t)bh * S_ * HD;
    const u16* Vb = VT + (size_t)bh * HD * S_;

    // double-buffered K/V tiles: 64 rows x 64 elems bf16 each = 8KB; total 32KB
    __shared__ __align__(16) u16 kbuf[2][64 * 64];
    __shared__ __align__(16) u16 vbuf[2][64 * 64];

    bf16x8 aq[2][2];
    #pragma unroll
    for (int mi = 0; mi < 2; ++mi)
        #pragma unroll
        for (int kk = 0; kk < 2; ++kk)
            aq[mi][kk] = *(const bf16x8*)(Qb + (size_t)(q0w + mi * 16 + lr) * HD + kk * 32 + quad * 8);

    f32x4 o[2][4] = {};
    f32x4 lacc[2] = {};
    bf16x8 ones;
    #pragma unroll
    for (int j = 0; j < 8; ++j) ones[j] = (short)0x3F80;   // bf16 1.0

    const int KT  = 2 * qc + 1;                 // block-uniform last tile
    const int ktw = (q0w + 31) >> 6;            // this wave's last tile

    // staging: 512 chunks of 16B per tile per matrix; wave w, instr j covers
    // chunks (j*4+w)*64 + lane -> 8 consecutive rows, XOR-permuted within row
    // (source pre-swizzled so LDS holds lds[row][c^(row&7)]; dest stays linear).
#define STAGE_KV(b, kk0) do {                                                   \
        _Pragma("unroll")                                                       \
        for (int j = 0; j < 2; ++j) {                                           \
            int ch  = ((j * 4 + wave) << 6) + lane;                             \
            int row = ch >> 3;                                                  \
            int cl  = (ch & 7) ^ (row & 7);                                     \
            GLD_LDS(Kb + (size_t)((kk0) + row) * HD + cl * 8, &kbuf[b][ch * 8]);\
            GLD_LDS(Vb + (size_t)row * S_ + (kk0) + cl * 8, &vbuf[b][ch * 8]);  \
        }                                                                       \
    } while (0)

    STAGE_KV(0, 0);
    __syncthreads();

    for (int kt = 0; kt <= KT; ++kt) {
        const int cur = kt & 1;
        if (kt < KT) STAGE_KV(cur ^ 1, (kt + 1) << 6);   // prefetch next tile

        if (kt <= ktw) {                                  // wave-uniform guard
            const int k0 = kt << 6;

            // K fragments from LDS (swizzled read)
            bf16x8 bk[4][2];
            #pragma unroll
            for (int t = 0; t < 4; ++t)
                #pragma unroll
                for (int kk = 0; kk < 2; ++kk) {
                    int row = t * 16 + lr;
                    int cp  = (kk * 4 + quad) ^ (row & 7);
                    bk[t][kk] = *(const bf16x8*)(&kbuf[cur][row * 64 + cp * 8]);
                }

            // swapped QK^T: lane holds q=lr, key=16t+quad*4+r
            f32x4 sT[2][4];
            #pragma unroll
            for (int mi = 0; mi < 2; ++mi)
                #pragma unroll
                for (int t = 0; t < 4; ++t) {
                    f32x4 z = {0.f, 0.f, 0.f, 0.f};
                    z = __builtin_amdgcn_mfma_f32_16x16x32_bf16(bk[t][0], aq[mi][0], z, 0, 0, 0);
                    z = __builtin_amdgcn_mfma_f32_16x16x32_bf16(bk[t][1], aq[mi][1], z, 0, 0, 0);
                    sT[mi][t] = z;
                }

            if (kt == ktw) {   // diagonal tile: causal mask (exp2(-inf) = 0)
                #pragma unroll
                for (int mi = 0; mi < 2; ++mi) {
                    int qrow = q0w + mi * 16 + lr;
                    #pragma unroll
                    for (int t = 0; t < 4; ++t)
                        #pragma unroll
                        for (int r = 0; r < 4; ++r) {
                            int key = k0 + t * 16 + quad * 4 + r;
                            if (key > qrow) sT[mi][t][r] = -INFINITY;
                        }
                }
            }

            // V fragments from LDS (swizzled read)
            bf16x8 bv[4][2];
            #pragma unroll
            for (int nv = 0; nv < 4; ++nv)
                #pragma unroll
                for (int c2 = 0; c2 < 2; ++c2) {
                    int row = nv * 16 + lr;
                    int cp  = (c2 * 4 + quad) ^ (row & 7);
                    bv[nv][c2] = *(const bf16x8*)(&vbuf[cur][row * 64 + cp * 8]);
                }

            // exp (Q pre-scaled by scale*log2e) + in-register transpose to A-layout
            bf16x8 pa[2][2];
            #pragma unroll
            for (int mi = 0; mi < 2; ++mi) {
                #pragma unroll
                for (int t = 0; t < 4; ++t)
                    #pragma unroll
                    for (int r = 0; r < 4; ++r)
                        sT[mi][t][r] = exp2f(sT[mi][t][r]);

                #pragma unroll
                for (int c = 0; c < 2; ++c) {
                    unsigned u00 = pk2(sT[mi][2 * c + 0][0], sT[mi][2 * c + 0][1]);
                    unsigned u01 = pk2(sT[mi][2 * c + 0][2], sT[mi][2 * c + 0][3]);
                    unsigned u10 = pk2(sT[mi][2 * c + 1][0], sT[mi][2 * c + 1][1]);
                    unsigned u11 = pk2(sT[mi][2 * c + 1][2], sT[mi][2 * c + 1][3]);
                    swap32(u00, u10); swap16(u00, u10);
                    swap32(u01, u11); swap16(u01, u11);
                    u32x4 P = {u00, u01, u10, u11};
                    pa[mi][c] = __builtin_bit_cast(bf16x8, P);
                }
            }

            #pragma unroll
            for (int mi = 0; mi < 2; ++mi) {
                lacc[mi] = __builtin_amdgcn_mfma_f32_16x16x32_bf16(pa[mi][0], ones, lacc[mi], 0, 0, 0);
                lacc[mi] = __builtin_amdgcn_mfma_f32_16x16x32_bf16(pa[mi][1], ones, lacc[mi], 0, 0, 0);
                #pragma unroll
                for (int nv = 0; nv < 4; ++nv) {
                    o[mi][nv] = __builtin_amdgcn_mfma_f32_16x16x32_bf16(pa[mi][0], bv[nv][0], o[mi][nv], 0, 0, 0);
                    o[mi][nv] = __builtin_amdgcn_mfma_f32_16x16x32_bf16(pa[mi][1], bv[nv][1], o[mi][nv], 0, 0, 0);
                }
            }
        }

        __syncthreads();   // staging of kt+1 done; reads of buf[cur] done
    }
#undef STAGE_KV

    // -------- per-wave epilogue (no cross-wave reduction) --------
    const int bb = bh / NH, h = bh % NH;
    #pragma unroll
    for (int mi = 0; mi < 2; ++mi) {
        f32x4 inv;
        #pragma unroll
        for (int r = 0; r < 4; ++r) inv[r] = 1.0f / lacc[mi][r];
        #pragma unroll
        for (int nv = 0; nv < 4; ++nv)
            #pragma unroll
            for (int r = 0; r < 4; ++r)
                CTX[(size_t)(bb * S_ + q0w + mi * 16 + quad * 4 + r) * DM + h * HD + nv * 16 + lr]
                    = f2bf(o[mi][nv][r] * inv[r]);
    }
}

// ---------------- output projection GEMM (LDS-staged, fp32 out) ----------------
__global__ __launch_bounds__(256) void o_gemm(
    const u16* __restrict__ X, const u16* __restrict__ W,
    const float* __restrict__ bias, float* __restrict__ Out)
{
    __shared__ __align__(16) u16 As[128 * 32];
    __shared__ __align__(16) u16 Bs[128 * 32];

    const int mt = blockIdx.x / 6, nt = blockIdx.x % 6;
    const int lane = threadIdx.x & 63;
    const int lr = lane & 15, quad = lane >> 4;
    const int wave = threadIdx.x >> 6;
    const int m0 = mt * 128 + (wave & 1) * 64;
    const int n0 = nt * 128 + (wave >> 1) * 64;

    f32x4 acc[4][4] = {};
    gemm_core_128(X, W, mt * 128, nt * 128, As, Bs, acc);

    #pragma unroll
    for (int jj = 0; jj < 4; ++jj) {
        float bv = bias[n0 + jj * 16 + lr];
        #pragma unroll
        for (int i = 0; i < 4; ++i)
            #pragma unroll
            for (int r = 0; r < 4; ++r)
                Out[(size_t)(m0 + i * 16 + quad * 4 + r) * DM + n0 + jj * 16 + lr] = acc[i][jj][r] + bv;
    }
}

extern "C" void kernel_launch(void* const* d_in, const int* in_sizes, int n_in,
                              void* d_out, int out_size, void* d_ws, size_t ws_size,
                              hipStream_t stream) {
    const float* q  = (const float*)d_in[0];
    const float* k  = (const float*)d_in[1];
    const float* v  = (const float*)d_in[2];
    const float* WQ = (const float*)d_in[3];
    const float* bQ = (const float*)d_in[4];
    const float* WK = (const float*)d_in[5];
    const float* bK = (const float*)d_in[6];
    const float* WV = (const float*)d_in[7];
    const float* bV = (const float*)d_in[8];
    const float* WO = (const float*)d_in[9];
    const float* bO = (const float*)d_in[10];

    char* ws = (char*)d_ws;
    const size_t SZ_X = (size_t)MT * DM * 2;   // 12,582,912 B
    const size_t SZ_W = (size_t)DM * DM * 2;   //  1,179,648 B
    u16* Xq = (u16*)(ws);
    u16* Xk = (u16*)(ws + SZ_X);
    u16* Xv = (u16*)(ws + 2 * SZ_X);
    u16* Wq = (u16*)(ws + 3 * SZ_X);
    u16* Wk = (u16*)(ws + 3 * SZ_X + SZ_W);
    u16* Wv = (u16*)(ws + 3 * SZ_X + 2 * SZ_W);
    u16* Wo = (u16*)(ws + 3 * SZ_X + 3 * SZ_W);
    u16* Qh  = (u16*)(ws + 3 * SZ_X + 4 * SZ_W);
    u16* Kh  = (u16*)(ws + 4 * SZ_X + 4 * SZ_W);
    u16* VTh = (u16*)(ws + 5 * SZ_X + 4 * SZ_W);
    u16* CTX = Xq;   // Xq dead after qkv_gemm; reuse

    const int nX = MT * DM;    // 6,291,456
    const int nW = DM * DM;    //   589,824
    cvt3_kernel<<<3 * (nX / 1024), 256, 0, stream>>>(q, k, v, Xq, Xk, Xv, nX / 1024);
    cvt4_kernel<<<4 * (nW / 1024), 256, 0, stream>>>(WQ, WK, WV, WO, Wq, Wk, Wv, Wo, nW / 1024);

    qkv_gemm<<<1152, 256, 0, stream>>>(Xq, Xk, Xv, Wq, Wk, Wv, bQ, bK, bV, Qh, Kh, VTh);
    attn_kernel<<<768, 256, 0, stream>>>(Qh, Kh, VTh, CTX);
    o_gemm<<<384, 256, 0, stream>>>(CTX, Wo, bO, (float*)d_out);
}

// Round 6
// 270.882 us; speedup vs baseline: 1.2561x; 1.0148x over previous
//
#include <hip/hip_runtime.h>
#include <hip/hip_bf16.h>

#define DM 768
#define NH 12
#define HD 64
#define B_ 4
#define S_ 2048
#define MT (B_*S_)   // 8192 rows

typedef unsigned short u16;
typedef __attribute__((ext_vector_type(8))) short bf16x8;
typedef __attribute__((ext_vector_type(4))) float f32x4;
typedef __attribute__((ext_vector_type(4))) short s16x4;
typedef __attribute__((ext_vector_type(4))) unsigned u32x4;

__device__ __forceinline__ u16 f2bf(float f) {
    union { float f; unsigned u; } x; x.f = f;
    unsigned r = x.u + 0x7fffu + ((x.u >> 16) & 1u);   // RNE
    return (u16)(r >> 16);
}

__device__ __forceinline__ unsigned pk2(float a, float b) {
    union { __hip_bfloat162 h; unsigned u; } cv;
    cv.h = __float22bfloat162_rn(float2{a, b});
    return cv.u;
}

// gfx950 cross-lane half-swaps (both outputs live via "+v","+v"):
__device__ __forceinline__ void swap32(unsigned& a, unsigned& b) {
    asm volatile("v_permlane32_swap_b32 %0, %1" : "+v"(a), "+v"(b));
}
__device__ __forceinline__ void swap16(unsigned& a, unsigned& b) {
    asm volatile("v_permlane16_swap_b32 %0, %1" : "+v"(a), "+v"(b));
}

#define GLD_LDS(gp, lp) \
    __builtin_amdgcn_global_load_lds( \
        (const __attribute__((address_space(1))) void*)(gp), \
        (__attribute__((address_space(3))) void*)(lp), 16, 0, 0)

// ---------------- fused fp32 -> bf16 conversions ----------------
__global__ void cvt3_kernel(const float* __restrict__ s0, const float* __restrict__ s1,
                            const float* __restrict__ s2,
                            u16* __restrict__ d0, u16* __restrict__ d1, u16* __restrict__ d2,
                            int blocksPer) {
    int sel = blockIdx.x / blocksPer;           // uniform per block
    int rel = blockIdx.x % blocksPer;
    const float* s = (sel == 0) ? s0 : (sel == 1) ? s1 : s2;
    u16* d = (sel == 0) ? d0 : (sel == 1) ? d1 : d2;
    int i = (rel * 256 + threadIdx.x) * 4;
    float4 v = *(const float4*)(s + i);
    s16x4 o;
    o.x = (short)f2bf(v.x); o.y = (short)f2bf(v.y);
    o.z = (short)f2bf(v.z); o.w = (short)f2bf(v.w);
    *(s16x4*)(d + i) = o;
}

__global__ void cvt4_kernel(const float* __restrict__ s0, const float* __restrict__ s1,
                            const float* __restrict__ s2, const float* __restrict__ s3,
                            u16* __restrict__ d0, u16* __restrict__ d1,
                            u16* __restrict__ d2, u16* __restrict__ d3,
                            int blocksPer) {
    int sel = blockIdx.x / blocksPer;
    int rel = blockIdx.x % blocksPer;
    const float* s = (sel == 0) ? s0 : (sel == 1) ? s1 : (sel == 2) ? s2 : s3;
    u16* d = (sel == 0) ? d0 : (sel == 1) ? d1 : (sel == 2) ? d2 : d3;
    int i = (rel * 256 + threadIdx.x) * 4;
    float4 v = *(const float4*)(s + i);
    s16x4 o;
    o.x = (short)f2bf(v.x); o.y = (short)f2bf(v.y);
    o.z = (short)f2bf(v.z); o.w = (short)f2bf(v.w);
    *(s16x4*)(d + i) = o;
}

// ---------------- shared 128x128-tile MFMA core (m97 structure) ----------------
__device__ __forceinline__ void gemm_core_128(
    const u16* __restrict__ A, const u16* __restrict__ B,
    int m0, int n0, u16* As, u16* Bs, f32x4 acc[4][4])
{
    const int tid = threadIdx.x;
    const int lane = tid & 63;
    const int lr = lane & 15, quad = lane >> 4;
    const int wave = tid >> 6;
    const int wm = (wave & 1) * 64, wn = (wave >> 1) * 64;

    for (int ks = 0; ks < 24; ++ks) {
        #pragma unroll
        for (int r = 0; r < 2; ++r) {
            int idx = r * 256 + tid;
            int row = idx >> 2, col = (idx & 3) * 8;
            GLD_LDS(A + (size_t)(m0 + row) * DM + ks * 32 + col, As + idx * 8);
            GLD_LDS(B + (size_t)(n0 + row) * DM + ks * 32 + col, Bs + idx * 8);
        }
        __syncthreads();
        bf16x8 a[4], b[4];
        #pragma unroll
        for (int i = 0; i < 4; ++i) a[i] = *(const bf16x8*)(As + (wm + i * 16 + lr) * 32 + quad * 8);
        #pragma unroll
        for (int j = 0; j < 4; ++j) b[j] = *(const bf16x8*)(Bs + (wn + j * 16 + lr) * 32 + quad * 8);
        #pragma unroll
        for (int i = 0; i < 4; ++i)
            #pragma unroll
            for (int j = 0; j < 4; ++j)
                acc[i][j] = __builtin_amdgcn_mfma_f32_16x16x32_bf16(a[i], b[j], acc[i][j], 0, 0, 0);
        __syncthreads();
    }
}

// ---------------- fused QKV projection GEMM (LDS-staged) ----------------
// R6 (T1): XCD-aware bijective remap. Old t=mt*6+nt put the 6 blocks sharing one
// X-panel on 6 DIFFERENT XCDs (bid%8) -> each private L2 refetched the panel
// (FETCH 122MB vs ~41 ideal; vmcnt(0) drain sees HBM-miss latency). New map:
// xcd owns whole mt-groups; all 6 nt of a panel hit the same XCD L2, adjacent
// slots -> co-resident. 1152 = 8 XCD x 24 groups x 6 nt (bijective, nwg%8==0).
__global__ __launch_bounds__(256) void qkv_gemm(
    const u16* __restrict__ Xq, const u16* __restrict__ Xk, const u16* __restrict__ Xv,
    const u16* __restrict__ Wq, const u16* __restrict__ Wk, const u16* __restrict__ Wv,
    const float* __restrict__ bQ, const float* __restrict__ bK, const float* __restrict__ bV,
    u16* __restrict__ Qo, u16* __restrict__ Ko, u16* __restrict__ VTo)
{
    __shared__ __align__(16) u16 As[128 * 32];
    __shared__ __align__(16) u16 Bs[128 * 32];

    const int xcd  = blockIdx.x & 7;
    const int slot = blockIdx.x >> 3;           // 0..143
    const int nt   = slot % 6;
    const int gg   = xcd * 24 + slot / 6;       // global mt-group 0..191
    const int mat  = gg / 64;                   // uniform per block
    const int mt   = gg % 64;
    const u16* X = (mat == 0) ? Xq : (mat == 1 ? Xk : Xv);
    const u16* W = (mat == 0) ? Wq : (mat == 1 ? Wk : Wv);
    const float* bias = (mat == 0) ? bQ : (mat == 1 ? bK : bV);

    const int lane = threadIdx.x & 63;
    const int lr = lane & 15, quad = lane >> 4;
    const int wave = threadIdx.x >> 6;
    const int m0 = mt * 128 + (wave & 1) * 64;
    const int n0 = nt * 128 + (wave >> 1) * 64;

    f32x4 acc[4][4] = {};
    gemm_core_128(X, W, mt * 128, nt * 128, As, Bs, acc);

    const int bb = m0 / S_, s0 = m0 % S_, h = n0 / HD;
    if (mat < 2) {
        u16* O = (mat == 0) ? Qo : Ko;
        const float qs = (mat == 0) ? 0.18033688011112042f : 1.0f;  // (1/8)*log2(e)
        #pragma unroll
        for (int jj = 0; jj < 4; ++jj) {
            float bv = bias[n0 + jj * 16 + lr];
            #pragma unroll
            for (int i = 0; i < 4; ++i)
                #pragma unroll
                for (int r = 0; r < 4; ++r) {
                    int s = s0 + i * 16 + quad * 4 + r;
                    O[((size_t)(bb * NH + h) * S_ + s) * HD + jj * 16 + lr] = f2bf((acc[i][jj][r] + bv) * qs);
                }
        }
    } else {
        #pragma unroll
        for (int jj = 0; jj < 4; ++jj) {
            float bv = bias[n0 + jj * 16 + lr];
            #pragma unroll
            for (int i = 0; i < 4; ++i) {
                int s = s0 + i * 16 + quad * 4;
                s16x4 o;
                o.x = (short)f2bf(acc[i][jj][0] + bv);
                o.y = (short)f2bf(acc[i][jj][1] + bv);
                o.z = (short)f2bf(acc[i][jj][2] + bv);
                o.w = (short)f2bf(acc[i][jj][3] + bv);
                *(s16x4*)(VTo + ((size_t)(bb * NH + h) * HD + jj * 16 + lr) * S_ + s) = o;
            }
        }
    }
}

// ---------------- flash attention (causal, NO-max softmax) ----------------
// R5 structure (kept): block owns 128 q-rows (4 waves x 32); K/V tile staged once
// per block into double-buffered LDS via 16 coalesced global_load_lds; one barrier
// per tile; XOR swizzle both-sides; swapped QK^T + permlane transpose; per-wave
// epilogue (no cross-wave reduction).
__global__ __launch_bounds__(256, 3) void attn_kernel(
    const u16* __restrict__ Q, const u16* __restrict__ K,
    const u16* __restrict__ VT, u16* __restrict__ CTX)
{
    const int tid = threadIdx.x;
    const int wave = tid >> 6;
    const int lane = tid & 63;
    const int lr = lane & 15, quad = lane >> 4;

    const int xcd = blockIdx.x & 7;
    const int i2  = blockIdx.x >> 3;            // 0..95
    const int bh  = xcd * 6 + (i2 % 6);
    const int qc  = 15 - (i2 / 6);              // longest q-chunks first
    const int Q0  = qc * 128;
    const int q0w = Q0 + wave * 32;             // this wave's 32 q-rows

    const u16* Qb = Q  + (size_t)bh * S_ * HD;
    const u16* Kb = K  + (size_t)bh * S_ * HD;
    const u16* Vb = VT + (size_t)bh * HD * S_;

    // double-buffered K/V tiles: 64 rows x 64 elems bf16 each = 8KB; total 32KB
    __shared__ __align__(16) u16 kbuf[2][64 * 64];
    __shared__ __align__(16) u16 vbuf[2][64 * 64];

    bf16x8 aq[2][2];
    #pragma unroll
    for (int mi = 0; mi < 2; ++mi)
        #pragma unroll
        for (int kk = 0; kk < 2; ++kk)
            aq[mi][kk] = *(const bf16x8*)(Qb + (size_t)(q0w + mi * 16 + lr) * HD + kk * 32 + quad * 8);

    f32x4 o[2][4] = {};
    f32x4 lacc[2] = {};
    bf16x8 ones;
    #pragma unroll
    for (int j = 0; j < 8; ++j) ones[j] = (short)0x3F80;   // bf16 1.0

    const int KT  = 2 * qc + 1;                 // block-uniform last tile
    const int ktw = (q0w + 31) >> 6;            // this wave's last tile

#define STAGE_KV(b, kk0) do {                                                   \
        _Pragma("unroll")                                                       \
        for (int j = 0; j < 2; ++j) {                                           \
            int ch  = ((j * 4 + wave) << 6) + lane;                             \
            int row = ch >> 3;                                                  \
            int cl  = (ch & 7) ^ (row & 7);                                     \
            GLD_LDS(Kb + (size_t)((kk0) + row) * HD + cl * 8, &kbuf[b][ch * 8]);\
            GLD_LDS(Vb + (size_t)row * S_ + (kk0) + cl * 8, &vbuf[b][ch * 8]);  \
        }                                                                       \
    } while (0)

    STAGE_KV(0, 0);
    __syncthreads();

    for (int kt = 0; kt <= KT; ++kt) {
        const int cur = kt & 1;
        if (kt < KT) STAGE_KV(cur ^ 1, (kt + 1) << 6);   // prefetch next tile

        if (kt <= ktw) {                                  // wave-uniform guard
            const int k0 = kt << 6;

            // K fragments from LDS (swizzled read)
            bf16x8 bk[4][2];
            #pragma unroll
            for (int t = 0; t < 4; ++t)
                #pragma unroll
                for (int kk = 0; kk < 2; ++kk) {
                    int row = t * 16 + lr;
                    int cp  = (kk * 4 + quad) ^ (row & 7);
                    bk[t][kk] = *(const bf16x8*)(&kbuf[cur][row * 64 + cp * 8]);
                }

            // swapped QK^T: lane holds q=lr, key=16t+quad*4+r
            f32x4 sT[2][4];
            #pragma unroll
            for (int mi = 0; mi < 2; ++mi)
                #pragma unroll
                for (int t = 0; t < 4; ++t) {
                    f32x4 z = {0.f, 0.f, 0.f, 0.f};
                    z = __builtin_amdgcn_mfma_f32_16x16x32_bf16(bk[t][0], aq[mi][0], z, 0, 0, 0);
                    z = __builtin_amdgcn_mfma_f32_16x16x32_bf16(bk[t][1], aq[mi][1], z, 0, 0, 0);
                    sT[mi][t] = z;
                }

            if (kt == ktw) {   // diagonal tile: causal mask (exp2(-inf) = 0)
                #pragma unroll
                for (int mi = 0; mi < 2; ++mi) {
                    int qrow = q0w + mi * 16 + lr;
                    #pragma unroll
                    for (int t = 0; t < 4; ++t)
                        #pragma unroll
                        for (int r = 0; r < 4; ++r) {
                            int key = k0 + t * 16 + quad * 4 + r;
                            if (key > qrow) sT[mi][t][r] = -INFINITY;
                        }
                }
            }

            // V fragments from LDS (swizzled read)
            bf16x8 bv[4][2];
            #pragma unroll
            for (int nv = 0; nv < 4; ++nv)
                #pragma unroll
                for (int c2 = 0; c2 < 2; ++c2) {
                    int row = nv * 16 + lr;
                    int cp  = (c2 * 4 + quad) ^ (row & 7);
                    bv[nv][c2] = *(const bf16x8*)(&vbuf[cur][row * 64 + cp * 8]);
                }

            // exp (Q pre-scaled by scale*log2e) + in-register transpose to A-layout
            bf16x8 pa[2][2];
            #pragma unroll
            for (int mi = 0; mi < 2; ++mi) {
                #pragma unroll
                for (int t = 0; t < 4; ++t)
                    #pragma unroll
                    for (int r = 0; r < 4; ++r)
                        sT[mi][t][r] = exp2f(sT[mi][t][r]);

                #pragma unroll
                for (int c = 0; c < 2; ++c) {
                    unsigned u00 = pk2(sT[mi][2 * c + 0][0], sT[mi][2 * c + 0][1]);
                    unsigned u01 = pk2(sT[mi][2 * c + 0][2], sT[mi][2 * c + 0][3]);
                    unsigned u10 = pk2(sT[mi][2 * c + 1][0], sT[mi][2 * c + 1][1]);
                    unsigned u11 = pk2(sT[mi][2 * c + 1][2], sT[mi][2 * c + 1][3]);
                    swap32(u00, u10); swap16(u00, u10);
                    swap32(u01, u11); swap16(u01, u11);
                    u32x4 P = {u00, u01, u10, u11};
                    pa[mi][c] = __builtin_bit_cast(bf16x8, P);
                }
            }

            #pragma unroll
            for (int mi = 0; mi < 2; ++mi) {
                lacc[mi] = __builtin_amdgcn_mfma_f32_16x16x32_bf16(pa[mi][0], ones, lacc[mi], 0, 0, 0);
                lacc[mi] = __builtin_amdgcn_mfma_f32_16x16x32_bf16(pa[mi][1], ones, lacc[mi], 0, 0, 0);
                #pragma unroll
                for (int nv = 0; nv < 4; ++nv) {
                    o[mi][nv] = __builtin_amdgcn_mfma_f32_16x16x32_bf16(pa[mi][0], bv[nv][0], o[mi][nv], 0, 0, 0);
                    o[mi][nv] = __builtin_amdgcn_mfma_f32_16x16x32_bf16(pa[mi][1], bv[nv][1], o[mi][nv], 0, 0, 0);
                }
            }
        }

        __syncthreads();   // staging of kt+1 done; reads of buf[cur] done
    }
#undef STAGE_KV

    // -------- per-wave epilogue (no cross-wave reduction) --------
    const int bb = bh / NH, h = bh % NH;
    #pragma unroll
    for (int mi = 0; mi < 2; ++mi) {
        f32x4 inv;
        #pragma unroll
        for (int r = 0; r < 4; ++r) inv[r] = 1.0f / lacc[mi][r];
        #pragma unroll
        for (int nv = 0; nv < 4; ++nv)
            #pragma unroll
            for (int r = 0; r < 4; ++r)
                CTX[(size_t)(bb * S_ + q0w + mi * 16 + quad * 4 + r) * DM + h * HD + nv * 16 + lr]
                    = f2bf(o[mi][nv][r] * inv[r]);
    }
}

// ---------------- output projection GEMM (LDS-staged, fp32 out) ----------------
// R6 (T1): same XCD-aware bijective remap as qkv_gemm. 384 = 8 XCD x 8 mt x 6 nt.
__global__ __launch_bounds__(256) void o_gemm(
    const u16* __restrict__ X, const u16* __restrict__ W,
    const float* __restrict__ bias, float* __restrict__ Out)
{
    __shared__ __align__(16) u16 As[128 * 32];
    __shared__ __align__(16) u16 Bs[128 * 32];

    const int xcd  = blockIdx.x & 7;
    const int slot = blockIdx.x >> 3;           // 0..47
    const int nt   = slot % 6;
    const int mt   = xcd * 8 + slot / 6;        // 0..63
    const int lane = threadIdx.x & 63;
    const int lr = lane & 15, quad = lane >> 4;
    const int wave = threadIdx.x >> 6;
    const int m0 = mt * 128 + (wave & 1) * 64;
    const int n0 = nt * 128 + (wave >> 1) * 64;

    f32x4 acc[4][4] = {};
    gemm_core_128(X, W, mt * 128, nt * 128, As, Bs, acc);

    #pragma unroll
    for (int jj = 0; jj < 4; ++jj) {
        float bv = bias[n0 + jj * 16 + lr];
        #pragma unroll
        for (int i = 0; i < 4; ++i)
            #pragma unroll
            for (int r = 0; r < 4; ++r)
                Out[(size_t)(m0 + i * 16 + quad * 4 + r) * DM + n0 + jj * 16 + lr] = acc[i][jj][r] + bv;
    }
}

extern "C" void kernel_launch(void* const* d_in, const int* in_sizes, int n_in,
                              void* d_out, int out_size, void* d_ws, size_t ws_size,
                              hipStream_t stream) {
    const float* q  = (const float*)d_in[0];
    const float* k  = (const float*)d_in[1];
    const float* v  = (const float*)d_in[2];
    const float* WQ = (const float*)d_in[3];
    const float* bQ = (const float*)d_in[4];
    const float* WK = (const float*)d_in[5];
    const float* bK = (const float*)d_in[6];
    const float* WV = (const float*)d_in[7];
    const float* bV = (const float*)d_in[8];
    const float* WO = (const float*)d_in[9];
    const float* bO = (const float*)d_in[10];

    char* ws = (char*)d_ws;
    const size_t SZ_X = (size_t)MT * DM * 2;   // 12,582,912 B
    const size_t SZ_W = (size_t)DM * DM * 2;   //  1,179,648 B
    u16* Xq = (u16*)(ws);
    u16* Xk = (u16*)(ws + SZ_X);
    u16* Xv = (u16*)(ws + 2 * SZ_X);
    u16* Wq = (u16*)(ws + 3 * SZ_X);
    u16* Wk = (u16*)(ws + 3 * SZ_X + SZ_W);
    u16* Wv = (u16*)(ws + 3 * SZ_X + 2 * SZ_W);
    u16* Wo = (u16*)(ws + 3 * SZ_X + 3 * SZ_W);
    u16* Qh  = (u16*)(ws + 3 * SZ_X + 4 * SZ_W);
    u16* Kh  = (u16*)(ws + 4 * SZ_X + 4 * SZ_W);
    u16* VTh = (u16*)(ws + 5 * SZ_X + 4 * SZ_W);
    u16* CTX = Xq;   // Xq dead after qkv_gemm; reuse

    const int nX = MT * DM;    // 6,291,456
    const int nW = DM * DM;    //   589,824
    cvt3_kernel<<<3 * (nX / 1024), 256, 0, stream>>>(q, k, v, Xq, Xk, Xv, nX / 1024);
    cvt4_kernel<<<4 * (nW / 1024), 256, 0, stream>>>(WQ, WK, WV, WO, Wq, Wk, Wv, Wo, nW / 1024);

    qkv_gemm<<<1152, 256, 0, stream>>>(Xq, Xk, Xv, Wq, Wk, Wv, bQ, bK, bV, Qh, Kh, VTh);
    attn_kernel<<<768, 256, 0, stream>>>(Qh, Kh, VTh, CTX);
    o_gemm<<<384, 256, 0, stream>>>(CTX, Wo, bO, (float*)d_out);
}